// Round 1
// baseline (143.696 us; speedup 1.0000x reference)
//
#include <hip/hip_runtime.h>
#include <hip/hip_bf16.h>

#define NB 16
#define CI 512
#define CO 512
#define HW 1024
#define SD 512
#define EPSI 1e-8f

typedef __attribute__((ext_vector_type(8))) short bf16x8;
typedef __attribute__((ext_vector_type(4))) float f32x4;
typedef __attribute__((ext_vector_type(4))) unsigned int u32x4;

// ---- style[b][c] = dot(w[b,:], style_w[c,:]) + style_b[c]
__global__ void k_style(const float* __restrict__ w, const float* __restrict__ sw,
                        const float* __restrict__ sb, float* __restrict__ style) {
    int idx = blockIdx.x * 256 + threadIdx.x;       // 0..8191
    int b = idx >> 9, c = idx & 511;
    const float4* wr = (const float4*)(w + b * SD);
    const float4* sr = (const float4*)(sw + c * SD);
    float acc = 0.f;
#pragma unroll 8
    for (int s = 0; s < SD / 4; ++s) {
        float4 a = wr[s], q = sr[s];
        acc += a.x * q.x + a.y * q.y + a.z * q.z + a.w * q.w;
    }
    style[idx] = acc + sb[c];
}

// ---- wsq[co][ci] = sum_t weight^2 ; also write Wt[t][co][ci] bf16 (tap-major transpose)
__global__ void k_wprep(const float* __restrict__ wt, float* __restrict__ wsq,
                        __hip_bfloat16* __restrict__ wtb) {
    int idx = blockIdx.x * 256 + threadIdx.x;       // co*512+ci, 0..262143
    const float* p = wt + idx * 9;
    float a = 0.f;
#pragma unroll
    for (int t = 0; t < 9; ++t) {
        float v = p[t];
        a += v * v;
        wtb[t * (CO * CI) + idx] = __float2bfloat16(v);
    }
    wsq[idx] = a;
}

// ---- d[b][co] = rsqrt(sum_ci style^2 * wsq + eps)
__global__ void k_demod(const float* __restrict__ style, const float* __restrict__ wsq,
                        float* __restrict__ dv) {
    int idx = blockIdx.x * 256 + threadIdx.x;       // 0..8191
    int b = idx >> 9, co = idx & 511;
    const float* st = style + b * CI;
    const float* wq = wsq + co * CI;
    float a = 0.f;
#pragma unroll 4
    for (int ci = 0; ci < CI; ++ci) {
        float s = st[ci];
        a += s * s * wq[ci];
    }
    dv[idx] = rsqrtf(a + EPSI);
}

// ---- xs[b][p][ci] = bf16(style[b][ci] * x[b][ci][p])   (transpose to ci-innermost)
__global__ void k_xs(const float* __restrict__ x, const float* __restrict__ style,
                     __hip_bfloat16* __restrict__ xs) {
    __shared__ float tile[32][33];
    int b = blockIdx.z, c0 = blockIdx.y * 32, p0 = blockIdx.x * 32;
    int tx = threadIdx.x & 31, ty = threadIdx.x >> 5;   // ty 0..7
#pragma unroll
    for (int i = 0; i < 4; ++i) {
        int ci = c0 + ty + i * 8;
        tile[ty + i * 8][tx] = x[(b * CI + ci) * HW + p0 + tx] * style[b * CI + ci];
    }
    __syncthreads();
#pragma unroll
    for (int i = 0; i < 4; ++i) {
        int p = p0 + ty + i * 8;
        xs[(b * HW + p) * CI + c0 + tx] = __float2bfloat16(tile[tx][ty + i * 8]);
    }
}

// ---- implicit-GEMM conv: out[b][co][p] = d[b][co] * sum_{t,ci} Wt[t][co][ci]*xs[b][p+shift(t)][ci]
#define BM 128
#define BN 128
#define CK 64
#define XBYTES (6 * 34 * 128)   // halo tile: 6 rows x 34 cols x 64ci bf16 (swizzled)

__global__ __launch_bounds__(256) void k_conv(
        const __hip_bfloat16* __restrict__ Wt,
        const __hip_bfloat16* __restrict__ xs,
        const float* __restrict__ dvec,
        float* __restrict__ out) {
    __shared__ alignas(16) char smem[XBYTES + BM * 128];
    char* Xs = smem;
    char* Ws = smem + XBYTES;

    const int tid = threadIdx.x;
    const int b   = blockIdx.z;
    const int co0 = blockIdx.y * BM;
    const int p0  = blockIdx.x * BN;
    const int y0  = p0 >> 5;

    // zero the padding columns rx=0 and rx=33 (never overwritten by staging)
    if (tid < 96) {
        int ry = tid >> 4;
        int rx = (tid & 8) ? 33 : 0;
        int g  = tid & 7;
        u32x4 z = {0, 0, 0, 0};
        *(u32x4*)(Xs + (ry * 34 + rx) * 128 + ((g ^ (rx & 7)) << 4)) = z;
    }

    const int lane = tid & 63;
    const int wv = tid >> 6;
    const int wr = wv >> 1, wc = wv & 1;
    const int lr = lane & 15;    // M/N index within fragment
    const int lk = lane >> 4;    // k-group 0..3

    f32x4 acc[4][4];
#pragma unroll
    for (int m = 0; m < 4; ++m)
#pragma unroll
        for (int n = 0; n < 4; ++n)
            acc[m][n] = (f32x4){0.f, 0.f, 0.f, 0.f};

    for (int cc = 0; cc < CI / CK; ++cc) {
        const int ci0 = cc * CK;
        __syncthreads();
        // stage X halo: 6 rows x 32 cols x 8 groups = 1536 16B-units, 6 per thread
#pragma unroll
        for (int k = 0; k < 6; ++k) {
            int u    = tid + (k << 8);
            int ry   = u >> 8;
            int rem  = u & 255;
            int xcol = rem >> 3;
            int g    = rem & 7;
            int y = y0 - 1 + ry;
            u32x4 v = {0, 0, 0, 0};
            if ((unsigned)y < 32u)
                v = *(const u32x4*)(xs + (b * HW + (y << 5) + xcol) * CI + ci0 + (g << 3));
            int rx = xcol + 1;
            *(u32x4*)(Xs + (ry * 34 + rx) * 128 + ((g ^ (rx & 7)) << 4)) = v;
        }
        const __hip_bfloat16* wsrc = Wt + (size_t)co0 * CI + ci0;
        for (int t = 0; t < 9; ++t) {
            __syncthreads();
            const __hip_bfloat16* wsrct = wsrc + (size_t)t * (CO * CI);
            // stage W tap tile: 128co x 64ci = 1024 16B-units, 4 per thread
#pragma unroll
            for (int k = 0; k < 4; ++k) {
                int u  = tid + (k << 8);
                int co = u >> 3;
                int g  = u & 7;
                u32x4 v = *(const u32x4*)(wsrct + co * CI + (g << 3));
                *(u32x4*)(Ws + co * 128 + ((g ^ (co & 7)) << 4)) = v;
            }
            __syncthreads();
            const int ky = t / 3, kx = t - ky * 3;
#pragma unroll
            for (int ks = 0; ks < 2; ++ks) {
                bf16x8 afr[4], bfr[4];
#pragma unroll
                for (int m = 0; m < 4; ++m) {
                    int co = wr * 64 + m * 16 + lr;
                    int g  = ks * 4 + lk;
                    afr[m] = *(const bf16x8*)(Ws + co * 128 + ((g ^ (co & 7)) << 4));
                }
#pragma unroll
                for (int n = 0; n < 4; ++n) {
                    int px = wc * 64 + n * 16 + lr;
                    int ry = (px >> 5) + ky;
                    int rx = (px & 31) + kx;
                    int g  = ks * 4 + lk;
                    bfr[n] = *(const bf16x8*)(Xs + (ry * 34 + rx) * 128 + ((g ^ (rx & 7)) << 4));
                }
#pragma unroll
                for (int m = 0; m < 4; ++m)
#pragma unroll
                    for (int n = 0; n < 4; ++n)
                        acc[m][n] = __builtin_amdgcn_mfma_f32_16x16x32_bf16(afr[m], bfr[n], acc[m][n], 0, 0, 0);
            }
        }
    }

    // epilogue: scale by d[b][co], store f32
#pragma unroll
    for (int m = 0; m < 4; ++m) {
#pragma unroll
        for (int r = 0; r < 4; ++r) {
            int co = co0 + wr * 64 + m * 16 + lk * 4 + r;
            float dvv = dvec[b * CO + co];
            float* orow = out + (size_t)(b * CO + co) * HW + p0;
#pragma unroll
            for (int n = 0; n < 4; ++n) {
                int px = wc * 64 + n * 16 + lr;
                orow[px] = acc[m][n][r] * dvv;
            }
        }
    }
}

extern "C" void kernel_launch(void* const* d_in, const int* in_sizes, int n_in,
                              void* d_out, int out_size, void* d_ws, size_t ws_size,
                              hipStream_t stream) {
    const float* x  = (const float*)d_in[0];
    const float* w  = (const float*)d_in[1];
    const float* sw = (const float*)d_in[2];
    const float* sb = (const float*)d_in[3];
    const float* wt = (const float*)d_in[4];
    float* out = (float*)d_out;

    char* ws = (char*)d_ws;
    float* style = (float*)(ws);                               // 32 KB
    float* dvec  = (float*)(ws + 32768);                       // 32 KB
    float* wsq   = (float*)(ws + 65536);                       // 1 MB
    __hip_bfloat16* wtb = (__hip_bfloat16*)(ws + 1114112);     // 4.72 MB
    __hip_bfloat16* xsb = (__hip_bfloat16*)(ws + 5832704);     // 16.78 MB

    k_style<<<32, 256, 0, stream>>>(w, sw, sb, style);
    k_wprep<<<1024, 256, 0, stream>>>(wt, wsq, wtb);
    k_demod<<<32, 256, 0, stream>>>(style, wsq, dvec);
    k_xs<<<dim3(32, 16, 16), 256, 0, stream>>>(x, style, xsb);
    k_conv<<<dim3(8, 4, 16), 256, 0, stream>>>(wtb, xsb, dvec, out);
}

// Round 2
// 100.628 us; speedup vs baseline: 1.4280x; 1.4280x over previous
//
#include <hip/hip_runtime.h>
#include <hip/hip_bf16.h>

#define NB 16
#define CI 512
#define CO 512
#define HW 1024
#define SD 512
#define EPSI 1e-8f

typedef __attribute__((ext_vector_type(8))) short bf16x8;
typedef __attribute__((ext_vector_type(16))) float f32x16;
typedef __attribute__((ext_vector_type(4))) unsigned int u32x4;

#define GLOAD_LDS16(g, l) __builtin_amdgcn_global_load_lds( \
    (const __attribute__((address_space(1))) unsigned int*)(const void*)(g), \
    (__attribute__((address_space(3))) unsigned int*)(void*)(l), 16, 0, 0)

// ---- style[b][c] = dot(w[b,:], style_w[c,:]) + style_b[c]  (one wave per output)
__global__ void k_style2(const float* __restrict__ w, const float* __restrict__ sw,
                         const float* __restrict__ sb, float* __restrict__ style) {
    int gw = (blockIdx.x * 256 + threadIdx.x) >> 6;   // 0..8191
    int l = threadIdx.x & 63;
    int b = gw >> 9, c = gw & 511;
    const float4* wr = (const float4*)(w + b * SD) + (l << 1);
    const float4* sr = (const float4*)(sw + c * SD) + (l << 1);
    float4 a0 = wr[0], a1 = wr[1], q0 = sr[0], q1 = sr[1];
    float acc = a0.x * q0.x + a0.y * q0.y + a0.z * q0.z + a0.w * q0.w
              + a1.x * q1.x + a1.y * q1.y + a1.z * q1.z + a1.w * q1.w;
#pragma unroll
    for (int off = 32; off > 0; off >>= 1) acc += __shfl_down(acc, off);
    if (l == 0) style[gw] = acc + sb[c];
}

// ---- wsq[co][ci] = sum_t weight^2 ; also write Wt[t][co][ci] bf16 (tap-major transpose)
__global__ void k_wprep(const float* __restrict__ wt, float* __restrict__ wsq,
                        __hip_bfloat16* __restrict__ wtb) {
    int idx = blockIdx.x * 256 + threadIdx.x;       // co*512+ci
    const float* p = wt + idx * 9;
    float a = 0.f;
#pragma unroll
    for (int t = 0; t < 9; ++t) {
        float v = p[t];
        a += v * v;
        wtb[t * (CO * CI) + idx] = __float2bfloat16(v);
    }
    wsq[idx] = a;
}

// ---- d[b][co] = rsqrt(sum_ci style^2 * wsq + eps)  (one wave per output)
__global__ void k_demod2(const float* __restrict__ style, const float* __restrict__ wsq,
                         float* __restrict__ dv) {
    int gw = (blockIdx.x * 256 + threadIdx.x) >> 6;
    int l = threadIdx.x & 63;
    int b = gw >> 9, co = gw & 511;
    const float4* st = (const float4*)(style + b * CI) + (l << 1);
    const float4* wq = (const float4*)(wsq + co * CI) + (l << 1);
    float4 s0 = st[0], s1 = st[1], q0 = wq[0], q1 = wq[1];
    float acc = s0.x * s0.x * q0.x + s0.y * s0.y * q0.y + s0.z * s0.z * q0.z + s0.w * s0.w * q0.w
              + s1.x * s1.x * q1.x + s1.y * s1.y * q1.y + s1.z * s1.z * q1.z + s1.w * s1.w * q1.w;
#pragma unroll
    for (int off = 32; off > 0; off >>= 1) acc += __shfl_down(acc, off);
    if (l == 0) dv[gw] = rsqrtf(acc + EPSI);
}

// ---- xs[b][p][ci] = bf16(style[b][ci] * x[b][ci][p])   (transpose to ci-innermost)
__global__ void k_xs(const float* __restrict__ x, const float* __restrict__ style,
                     __hip_bfloat16* __restrict__ xs) {
    __shared__ float tile[32][33];
    int b = blockIdx.z, c0 = blockIdx.y * 32, p0 = blockIdx.x * 32;
    int tx = threadIdx.x & 31, ty = threadIdx.x >> 5;
#pragma unroll
    for (int i = 0; i < 4; ++i) {
        int ci = c0 + ty + i * 8;
        tile[ty + i * 8][tx] = x[(b * CI + ci) * HW + p0 + tx] * style[b * CI + ci];
    }
    __syncthreads();
#pragma unroll
    for (int i = 0; i < 4; ++i) {
        int p = p0 + ty + i * 8;
        xs[(b * HW + p) * CI + c0 + tx] = __float2bfloat16(tile[tx][ty + i * 8]);
    }
}

// ---- conv: 1 block = 128co x 128px x 2 batches; 4 waves, per-wave 128co x 64px (32x32x16 MFMA)
// LDS: Xs 2*6*34*128 = 52224 B ; W double-buffer 2*16384 B ; total 84992 B
#define XS_BYTES 52224
#define WBUF_BYTES 16384

extern "C" __global__ __launch_bounds__(256, 1) void k_conv(
        const __hip_bfloat16* __restrict__ wtb,
        const __hip_bfloat16* __restrict__ xs,
        const float* __restrict__ dvec,
        float* __restrict__ out) {
    extern __shared__ char smem[];
    char* Xs  = smem;
    char* Wsb = smem + XS_BYTES;

    const int tid  = threadIdx.x;
    const int lane = tid & 63;
    const int wv   = tid >> 6;
    const int wn   = wv & 1;     // px half
    const int wb   = wv >> 1;    // batch within pair

    // XCD-aware swizzle: co-tile pinned per XCD pair so W tile (1.18MB) stays L2-resident
    int bid = blockIdx.x;
    int xcd = bid & 7, idx = bid >> 3;
    int cot = xcd >> 1;
    int px8 = idx & 7;
    int bp  = (idx >> 3) | ((xcd & 1) << 2);
    const int co0 = cot * 128;
    const int p0  = px8 * 128;
    const int y0  = px8 * 4;
    const int b0  = bp * 2;
    const int b   = b0 + wb;

    // zero halo pad columns rx=0 and rx=33 (stay zero for whole kernel)
    if (tid < 192) {
        int g = tid & 7;
        int rx = ((tid >> 3) & 1) ? 33 : 0;
        int row = tid >> 4;                  // bb*6+ry, 0..11
        *(u32x4*)(Xs + (row * 34 + rx) * 128 + g * 16) = (u32x4){0, 0, 0, 0};
    }

    f32x16 acc[4][2];
#pragma unroll
    for (int m = 0; m < 4; ++m)
#pragma unroll
        for (int n = 0; n < 2; ++n)
            acc[m][n] = (f32x16)(0.f);

    // prefetch W(tap0, cc0) into buf0
    {
        const __hip_bfloat16* wsrc = wtb + (size_t)co0 * CI;
        int srcg = (lane & 7) ^ (lane >> 3);
#pragma unroll
        for (int k = 0; k < 4; ++k) {
            int seg = k * 4 + wv;
            int co_l = seg * 8 + (lane >> 3);
            GLOAD_LDS16(wsrc + co_l * CI + srcg * 8, Wsb + seg * 1024);
        }
    }

    for (int cc = 0; cc < 8; ++cc) {
        const int ci0 = cc * 64;
        if (cc) __syncthreads();   // A-sync: safe to overwrite X tile
        // stage X halo (both batches): 48 wave-segments, 12 per wave
#pragma unroll
        for (int k = 0; k < 12; ++k) {
            int sid = k * 4 + wv;
            int bb = (k >= 6) ? 1 : 0;
            int rem = sid - bb * 24;
            int ry = rem >> 2, seg = rem & 3;
            int rx0 = 1 + seg * 8;
            char* ldst = Xs + ((bb * 6 + ry) * 34 + rx0) * 128;
            int y = y0 - 1 + ry;
            int rx = rx0 + (lane >> 3);
            int srcg = (lane & 7) ^ (rx & 7);
            if ((unsigned)y < 32u) {
                GLOAD_LDS16(xs + ((size_t)(b0 + bb) * HW + (y << 5) + (rx - 1)) * CI + ci0 + srcg * 8,
                            ldst);
            } else {
                *(u32x4*)(ldst + (lane << 4)) = (u32x4){0, 0, 0, 0};
            }
        }

#pragma unroll
        for (int t = 0; t < 9; ++t) {
            __syncthreads();   // B-sync: drains own vmcnt; staged data all landed
            // depth-1 W prefetch for next stage (next tap, or tap0 of next cc)
            if (cc * 9 + t < 71) {
                const int tn = (t == 8) ? 0 : (t + 1);
                const int cin = (t == 8) ? (ci0 + 64) : ci0;
                const __hip_bfloat16* wsrc = wtb + ((size_t)tn * CO + co0) * CI + cin;
                char* wdst = Wsb + (((cc + t + 1) & 1) ? WBUF_BYTES : 0);
                int srcg = (lane & 7) ^ (lane >> 3);
#pragma unroll
                for (int k = 0; k < 4; ++k) {
                    int seg = k * 4 + wv;
                    int co_l = seg * 8 + (lane >> 3);
                    GLOAD_LDS16(wsrc + co_l * CI + srcg * 8, wdst + seg * 1024);
                }
            }
            // MFMA for tap t from buf (cc+t)&1
            const char* Wb = Wsb + (((cc + t) & 1) ? WBUF_BYTES : 0);
            const int ky = t / 3, kx = t - (t / 3) * 3;
#pragma unroll
            for (int q = 0; q < 4; ++q) {
                bf16x8 afr[4], bfr[2];
                int g = (q << 1) + (lane >> 5);
#pragma unroll
                for (int m = 0; m < 4; ++m)
                    afr[m] = *(const bf16x8*)(Wb + (m * 32 + (lane & 31)) * 128 +
                                              ((g ^ (lane & 7)) << 4));
#pragma unroll
                for (int n = 0; n < 2; ++n) {
                    int ry = wn * 2 + n + ky;
                    int rx = (lane & 31) + kx;
                    bfr[n] = *(const bf16x8*)(Xs + ((wb * 6 + ry) * 34 + rx) * 128 +
                                              ((g ^ (rx & 7)) << 4));
                }
#pragma unroll
                for (int m = 0; m < 4; ++m)
#pragma unroll
                    for (int n = 0; n < 2; ++n)
                        acc[m][n] = __builtin_amdgcn_mfma_f32_32x32x16_bf16(afr[m], bfr[n], acc[m][n], 0, 0, 0);
            }
        }
    }

    // epilogue: d-scale + store f32. 32x32 C layout: col=lane&31, row=(r&3)+8*(r>>2)+4*(lane>>5)
#pragma unroll
    for (int m = 0; m < 4; ++m) {
#pragma unroll
        for (int r = 0; r < 16; ++r) {
            int co = co0 + m * 32 + (r & 3) + ((r >> 2) << 3) + ((lane >> 5) << 2);
            float dvv = dvec[b * CO + co];
            float* orow = out + ((size_t)b * CO + co) * HW + p0 + wn * 64;
            orow[lane & 31]      = acc[m][0][r] * dvv;
            orow[32 + (lane & 31)] = acc[m][1][r] * dvv;
        }
    }
}

extern "C" void kernel_launch(void* const* d_in, const int* in_sizes, int n_in,
                              void* d_out, int out_size, void* d_ws, size_t ws_size,
                              hipStream_t stream) {
    const float* x  = (const float*)d_in[0];
    const float* w  = (const float*)d_in[1];
    const float* sw = (const float*)d_in[2];
    const float* sb = (const float*)d_in[3];
    const float* wt = (const float*)d_in[4];
    float* out = (float*)d_out;

    char* ws = (char*)d_ws;
    float* style = (float*)(ws);                               // 32 KB
    float* dvec  = (float*)(ws + 32768);                       // 32 KB
    float* wsq   = (float*)(ws + 65536);                       // 1 MB
    __hip_bfloat16* wtb = (__hip_bfloat16*)(ws + 1114112);     // 4.72 MB
    __hip_bfloat16* xsb = (__hip_bfloat16*)(ws + 5832704);     // 16.78 MB

    hipFuncSetAttribute((const void*)k_conv,
                        hipFuncAttributeMaxDynamicSharedMemorySize, 84992);

    k_style2<<<2048, 256, 0, stream>>>(w, sw, sb, style);
    k_wprep<<<1024, 256, 0, stream>>>(wt, wsq, wtb);
    k_xs<<<dim3(32, 16, 16), 256, 0, stream>>>(x, style, xsb);
    k_demod2<<<2048, 256, 0, stream>>>(style, wsq, dvec);
    k_conv<<<256, 256, 84992, stream>>>(wtb, xsb, dvec, out);
}

// Round 3
// 97.693 us; speedup vs baseline: 1.4709x; 1.0300x over previous
//
#include <hip/hip_runtime.h>
#include <hip/hip_bf16.h>

#define NB 16
#define CI 512
#define CO 512
#define HW 1024
#define SD 512
#define EPSI 1e-8f

typedef __attribute__((ext_vector_type(8))) short bf16x8;
typedef __attribute__((ext_vector_type(16))) float f32x16;
typedef __attribute__((ext_vector_type(4))) unsigned int u32x4;

#define GLOAD_LDS16(g, l) __builtin_amdgcn_global_load_lds( \
    (const __attribute__((address_space(1))) unsigned int*)(const void*)(g), \
    (__attribute__((address_space(3))) unsigned int*)(void*)(l), 16, 0, 0)
#define SCHED0() __builtin_amdgcn_sched_barrier(0)
#define SBAR()   __builtin_amdgcn_s_barrier()

// ---- style[b][c] = dot(w[b,:], style_w[c,:]) + style_b[c]  (one wave per output)
__global__ void k_style2(const float* __restrict__ w, const float* __restrict__ sw,
                         const float* __restrict__ sb, float* __restrict__ style) {
    int gw = (blockIdx.x * 256 + threadIdx.x) >> 6;   // 0..8191
    int l = threadIdx.x & 63;
    int b = gw >> 9, c = gw & 511;
    const float4* wr = (const float4*)(w + b * SD) + (l << 1);
    const float4* sr = (const float4*)(sw + c * SD) + (l << 1);
    float4 a0 = wr[0], a1 = wr[1], q0 = sr[0], q1 = sr[1];
    float acc = a0.x * q0.x + a0.y * q0.y + a0.z * q0.z + a0.w * q0.w
              + a1.x * q1.x + a1.y * q1.y + a1.z * q1.z + a1.w * q1.w;
#pragma unroll
    for (int off = 32; off > 0; off >>= 1) acc += __shfl_down(acc, off);
    if (l == 0) style[gw] = acc + sb[c];
}

// ---- wsq[co][ci] = sum_t weight^2 ; also write Wt[t][co][ci] bf16 (tap-major transpose)
__global__ void k_wprep(const float* __restrict__ wt, float* __restrict__ wsq,
                        __hip_bfloat16* __restrict__ wtb) {
    int idx = blockIdx.x * 256 + threadIdx.x;       // co*512+ci
    const float* p = wt + idx * 9;
    float a = 0.f;
#pragma unroll
    for (int t = 0; t < 9; ++t) {
        float v = p[t];
        a += v * v;
        wtb[t * (CO * CI) + idx] = __float2bfloat16(v);
    }
    wsq[idx] = a;
}

// ---- d[b][co] = rsqrt(sum_ci style^2 * wsq + eps)  (one wave per output)
__global__ void k_demod2(const float* __restrict__ style, const float* __restrict__ wsq,
                         float* __restrict__ dv) {
    int gw = (blockIdx.x * 256 + threadIdx.x) >> 6;
    int l = threadIdx.x & 63;
    int b = gw >> 9, co = gw & 511;
    const float4* st = (const float4*)(style + b * CI) + (l << 1);
    const float4* wq = (const float4*)(wsq + co * CI) + (l << 1);
    float4 s0 = st[0], s1 = st[1], q0 = wq[0], q1 = wq[1];
    float acc = s0.x * s0.x * q0.x + s0.y * s0.y * q0.y + s0.z * s0.z * q0.z + s0.w * s0.w * q0.w
              + s1.x * s1.x * q1.x + s1.y * s1.y * q1.y + s1.z * s1.z * q1.z + s1.w * s1.w * q1.w;
#pragma unroll
    for (int off = 32; off > 0; off >>= 1) acc += __shfl_down(acc, off);
    if (l == 0) dv[gw] = rsqrtf(acc + EPSI);
}

// ---- xs[b][p][ci] = bf16(style[b][ci] * x[b][ci][p])   (transpose to ci-innermost)
__global__ void k_xs(const float* __restrict__ x, const float* __restrict__ style,
                     __hip_bfloat16* __restrict__ xs) {
    __shared__ float tile[32][33];
    int b = blockIdx.z, c0 = blockIdx.y * 32, p0 = blockIdx.x * 32;
    int tx = threadIdx.x & 31, ty = threadIdx.x >> 5;
#pragma unroll
    for (int i = 0; i < 4; ++i) {
        int ci = c0 + ty + i * 8;
        tile[ty + i * 8][tx] = x[(b * CI + ci) * HW + p0 + tx] * style[b * CI + ci];
    }
    __syncthreads();
#pragma unroll
    for (int i = 0; i < 4; ++i) {
        int p = p0 + ty + i * 8;
        xs[(b * HW + p) * CI + c0 + tx] = __float2bfloat16(tile[tx][ty + i * 8]);
    }
}

// ---- conv: 1 block = 128co x 128px x 2 batches; 4 waves, per-wave 128co x 64px (32x32x16 MFMA)
// T3/T4 schedule: raw s_barrier + counted vmcnt; X double-buffer, W triple-buffer (depth-2)
#define XS_BYTES 52224               // one X buffer: 2 batches x 6 rows x 34 cols x 128 B
#define WBUF_BYTES 16384             // one W buffer: 128co x 64ci bf16
#define SMEM_TOTAL (2 * XS_BYTES + 3 * WBUF_BYTES)   // 153600

extern "C" __global__ __launch_bounds__(256, 1) void k_conv(
        const __hip_bfloat16* __restrict__ wtb,
        const __hip_bfloat16* __restrict__ xs,
        const float* __restrict__ dvec,
        float* __restrict__ out) {
    extern __shared__ char smem[];
    char* Xs  = smem;                    // 2 buffers
    char* Wsb = smem + 2 * XS_BYTES;     // 3 buffers

    const int tid  = threadIdx.x;
    const int lane = tid & 63;
    const int wv   = tid >> 6;
    const int wn   = wv & 1;     // px half
    const int wb   = wv >> 1;    // batch within pair

    // XCD-aware swizzle: co-tile pinned per XCD pair so W tile stays L2-resident
    int bid = blockIdx.x;
    int xcd = bid & 7, idx = bid >> 3;
    int cot = xcd >> 1;
    int px8 = idx & 7;
    int bp  = (idx >> 3) | ((xcd & 1) << 2);
    const int co0 = cot * 128;
    const int p0  = px8 * 128;
    const int y0  = px8 * 4;
    const int b0  = bp * 2;
    const int b   = b0 + wb;
    const bool xedge = (px8 == 0) || (px8 == 7);   // 2 halo rows zero-filled -> 10 X gloads/wave

    // zero halo pad columns rx=0 and rx=33 in BOTH X buffers (stay zero for whole kernel)
    if (tid < 192) {
        int g = tid & 7;
        int rx = ((tid >> 3) & 1) ? 33 : 0;
        int row = tid >> 4;                  // bb*6+ry, 0..11
        int off = (row * 34 + rx) * 128 + g * 16;
        *(u32x4*)(Xs + off) = (u32x4){0, 0, 0, 0};
        *(u32x4*)(Xs + XS_BYTES + off) = (u32x4){0, 0, 0, 0};
    }

    const int srcgW = (lane & 7) ^ (lane >> 3);

    // ---- issue helpers (each wave issues its own loads; vmcnt ledger is per-wave)
    // W stage s -> buffer s%3 (9 taps => buf index == tap%3 since 9%3==0)
    auto issueW = [&](int tap, int cin, int bufi) {
        const __hip_bfloat16* wsrc = wtb + ((size_t)tap * CO + co0) * CI + cin;
        char* wdst = Wsb + bufi * WBUF_BYTES;
#pragma unroll
        for (int k = 0; k < 4; ++k) {
            int seg = k * 4 + wv;
            int co_l = seg * 8 + (lane >> 3);
            GLOAD_LDS16(wsrc + co_l * CI + srcgW * 8, wdst + seg * 1024);
        }
    };
    auto issueX = (void*)nullptr; (void)issueX;

    f32x16 acc[4][2];
#pragma unroll
    for (int m = 0; m < 4; ++m)
#pragma unroll
        for (int n = 0; n < 2; ++n)
            acc[m][n] = (f32x16)(0.f);

    // ---- prologue: W(0)->buf0, W(1)->buf1, X(0)->Xbuf0; full drain; barrier
    issueW(0, 0, 0);
    issueW(1, 0, 1);
    {
        char* Xdst = Xs;
#pragma unroll
        for (int k = 0; k < 12; ++k) {
            int sid = k * 4 + wv;
            int bb = (k >= 6) ? 1 : 0;
            int rem = sid - bb * 24;
            int ry = rem >> 2, seg = rem & 3;
            int rx0 = 1 + seg * 8;
            char* ldst = Xdst + ((bb * 6 + ry) * 34 + rx0) * 128;
            int y = y0 - 1 + ry;
            int rx = rx0 + (lane >> 3);
            int srcg = (lane & 7) ^ (rx & 7);
            if ((unsigned)y < 32u)
                GLOAD_LDS16(xs + ((size_t)(b0 + bb) * HW + (y << 5) + (rx - 1)) * CI + 0 + srcg * 8, ldst);
            else
                *(u32x4*)(ldst + (lane << 4)) = (u32x4){0, 0, 0, 0};
        }
    }
    SCHED0();
    asm volatile("s_waitcnt lgkmcnt(0) vmcnt(0)" ::: "memory");
    SCHED0();
    SBAR();
    SCHED0();

    for (int cc = 0; cc < 8; ++cc) {
        const char* Xcur = Xs + (cc & 1) * XS_BYTES;
#pragma unroll
        for (int t = 0; t < 9; ++t) {
            // ---- post-barrier issue region: W(s+2) (depth-2), X(cc+1) at tap0
            if (!(cc == 7 && t >= 7)) {
                const int tn  = (t <= 6) ? (t + 2) : (t - 7);
                const int cin = ((t <= 6) ? cc : (cc + 1)) * 64;
                issueW(tn, cin, (t + 2) % 3);
            }
            if (t == 0 && cc < 7) {
                char* Xdst = Xs + ((cc + 1) & 1) * XS_BYTES;
                const int cin = (cc + 1) * 64;
#pragma unroll
                for (int k = 0; k < 12; ++k) {
                    int sid = k * 4 + wv;
                    int bb = (k >= 6) ? 1 : 0;
                    int rem = sid - bb * 24;
                    int ry = rem >> 2, seg = rem & 3;
                    int rx0 = 1 + seg * 8;
                    char* ldst = Xdst + ((bb * 6 + ry) * 34 + rx0) * 128;
                    int y = y0 - 1 + ry;
                    int rx = rx0 + (lane >> 3);
                    int srcg = (lane & 7) ^ (rx & 7);
                    if ((unsigned)y < 32u)
                        GLOAD_LDS16(xs + ((size_t)(b0 + bb) * HW + (y << 5) + (rx - 1)) * CI + cin + srcg * 8, ldst);
                    else
                        *(u32x4*)(ldst + (lane << 4)) = (u32x4){0, 0, 0, 0};
                }
            }
            SCHED0();

            // ---- compute tap t from W buffer t%3 (compiler handles ds_read->MFMA lgkm deps)
            const char* Wb = Wsb + (t % 3) * WBUF_BYTES;
            const int ky = t / 3, kx = t - (t / 3) * 3;
#pragma unroll
            for (int q = 0; q < 4; ++q) {
                bf16x8 afr[4], bfr[2];
                int g = (q << 1) + (lane >> 5);
#pragma unroll
                for (int m = 0; m < 4; ++m)
                    afr[m] = *(const bf16x8*)(Wb + (m * 32 + (lane & 31)) * 128 +
                                              ((g ^ (lane & 7)) << 4));
#pragma unroll
                for (int n = 0; n < 2; ++n) {
                    int ry = wn * 2 + n + ky;
                    int rx = (lane & 31) + kx;
                    bfr[n] = *(const bf16x8*)(Xcur + ((wb * 6 + ry) * 34 + rx) * 128 +
                                              ((g ^ (rx & 7)) << 4));
                }
#pragma unroll
                for (int m = 0; m < 4; ++m)
#pragma unroll
                    for (int n = 0; n < 2; ++n)
                        acc[m][n] = __builtin_amdgcn_mfma_f32_32x32x16_bf16(afr[m], bfr[n], acc[m][n], 0, 0, 0);
            }

            // ---- pre-barrier counted wait (per-wave ledger; in-order vmcnt retire):
            // taps 0-1 (cc<7): outstanding after W(s+1) = W(s+2)(4) + X'(12 or 10 on edge)
            // taps 2-8:        outstanding after W(s+1) = W(s+2)(4)
            // cc==7,t==7:      only W(71) outstanding -> full drain
            if (!(cc == 7 && t == 8)) {   // no barrier after the very last tap
                SCHED0();
                if (cc < 7 && t < 2) {
                    if (xedge) asm volatile("s_waitcnt lgkmcnt(0) vmcnt(14)" ::: "memory");
                    else       asm volatile("s_waitcnt lgkmcnt(0) vmcnt(16)" ::: "memory");
                } else if (cc == 7 && t == 7) {
                    asm volatile("s_waitcnt lgkmcnt(0) vmcnt(0)" ::: "memory");
                } else {
                    asm volatile("s_waitcnt lgkmcnt(0) vmcnt(4)" ::: "memory");
                }
                SCHED0();
                SBAR();
                SCHED0();
            }
        }
    }

    // epilogue: d-scale + store f32. 32x32 C layout: col=lane&31, row=(r&3)+8*(r>>2)+4*(lane>>5)
#pragma unroll
    for (int m = 0; m < 4; ++m) {
#pragma unroll
        for (int r = 0; r < 16; ++r) {
            int co = co0 + m * 32 + (r & 3) + ((r >> 2) << 3) + ((lane >> 5) << 2);
            float dvv = dvec[b * CO + co];
            float* orow = out + ((size_t)b * CO + co) * HW + p0 + wn * 64;
            orow[lane & 31]        = acc[m][0][r] * dvv;
            orow[32 + (lane & 31)] = acc[m][1][r] * dvv;
        }
    }
}

extern "C" void kernel_launch(void* const* d_in, const int* in_sizes, int n_in,
                              void* d_out, int out_size, void* d_ws, size_t ws_size,
                              hipStream_t stream) {
    const float* x  = (const float*)d_in[0];
    const float* w  = (const float*)d_in[1];
    const float* sw = (const float*)d_in[2];
    const float* sb = (const float*)d_in[3];
    const float* wt = (const float*)d_in[4];
    float* out = (float*)d_out;

    char* ws = (char*)d_ws;
    float* style = (float*)(ws);                               // 32 KB
    float* dvec  = (float*)(ws + 32768);                       // 32 KB
    float* wsq   = (float*)(ws + 65536);                       // 1 MB
    __hip_bfloat16* wtb = (__hip_bfloat16*)(ws + 1114112);     // 4.72 MB
    __hip_bfloat16* xsb = (__hip_bfloat16*)(ws + 5832704);     // 16.78 MB

    hipFuncSetAttribute((const void*)k_conv,
                        hipFuncAttributeMaxDynamicSharedMemorySize, SMEM_TOTAL);

    k_style2<<<2048, 256, 0, stream>>>(w, sw, sb, style);
    k_wprep<<<1024, 256, 0, stream>>>(wt, wsq, wtb);
    k_xs<<<dim3(32, 16, 16), 256, 0, stream>>>(x, style, xsb);
    k_demod2<<<2048, 256, 0, stream>>>(style, wsq, dvec);
    k_conv<<<256, 256, SMEM_TOTAL, stream>>>(wtb, xsb, dvec, out);
}

// Round 4
// 94.995 us; speedup vs baseline: 1.5127x; 1.0284x over previous
//
#include <hip/hip_runtime.h>
#include <hip/hip_bf16.h>

#define NB 16
#define CI 512
#define CO 512
#define HW 1024
#define SD 512
#define EPSI 1e-8f

typedef __attribute__((ext_vector_type(8))) short bf16x8;
typedef __attribute__((ext_vector_type(16))) float f32x16;
typedef __attribute__((ext_vector_type(4))) unsigned int u32x4;

#define GLOAD_LDS16(g, l) __builtin_amdgcn_global_load_lds( \
    (const __attribute__((address_space(1))) unsigned int*)(const void*)(g), \
    (__attribute__((address_space(3))) unsigned int*)(void*)(l), 16, 0, 0)
#define SCHED0() __builtin_amdgcn_sched_barrier(0)
#define SBAR()   __builtin_amdgcn_s_barrier()

// ---- style[b][c] = dot(w[b,:], style_w[c,:]) + style_b[c]  (one wave per output)
__global__ void k_style2(const float* __restrict__ w, const float* __restrict__ sw,
                         const float* __restrict__ sb, float* __restrict__ style) {
    int gw = (blockIdx.x * 256 + threadIdx.x) >> 6;   // 0..8191
    int l = threadIdx.x & 63;
    int b = gw >> 9, c = gw & 511;
    const float4* wr = (const float4*)(w + b * SD) + (l << 1);
    const float4* sr = (const float4*)(sw + c * SD) + (l << 1);
    float4 a0 = wr[0], a1 = wr[1], q0 = sr[0], q1 = sr[1];
    float acc = a0.x * q0.x + a0.y * q0.y + a0.z * q0.z + a0.w * q0.w
              + a1.x * q1.x + a1.y * q1.y + a1.z * q1.z + a1.w * q1.w;
#pragma unroll
    for (int off = 32; off > 0; off >>= 1) acc += __shfl_down(acc, off);
    if (l == 0) style[gw] = acc + sb[c];
}

// ---- wsq[co][ci] = sum_t weight^2 ; write Wt[t][co][ci] bf16 ; zero the zpage
__global__ void k_wprep(const float* __restrict__ wt, float* __restrict__ wsq,
                        __hip_bfloat16* __restrict__ wtb, u32x4* __restrict__ zpage) {
    if (blockIdx.x == 0 && threadIdx.x < 64)
        zpage[threadIdx.x] = (u32x4){0, 0, 0, 0};
    int idx = blockIdx.x * 256 + threadIdx.x;       // co*512+ci
    const float* p = wt + idx * 9;
    float a = 0.f;
#pragma unroll
    for (int t = 0; t < 9; ++t) {
        float v = p[t];
        a += v * v;
        wtb[t * (CO * CI) + idx] = __float2bfloat16(v);
    }
    wsq[idx] = a;
}

// ---- d[b][co] = rsqrt(sum_ci style^2 * wsq + eps)  (one wave per output)
__global__ void k_demod2(const float* __restrict__ style, const float* __restrict__ wsq,
                         float* __restrict__ dv) {
    int gw = (blockIdx.x * 256 + threadIdx.x) >> 6;
    int l = threadIdx.x & 63;
    int b = gw >> 9, co = gw & 511;
    const float4* st = (const float4*)(style + b * CI) + (l << 1);
    const float4* wq = (const float4*)(wsq + co * CI) + (l << 1);
    float4 s0 = st[0], s1 = st[1], q0 = wq[0], q1 = wq[1];
    float acc = s0.x * s0.x * q0.x + s0.y * s0.y * q0.y + s0.z * s0.z * q0.z + s0.w * s0.w * q0.w
              + s1.x * s1.x * q1.x + s1.y * s1.y * q1.y + s1.z * s1.z * q1.z + s1.w * s1.w * q1.w;
#pragma unroll
    for (int off = 32; off > 0; off >>= 1) acc += __shfl_down(acc, off);
    if (l == 0) dv[gw] = rsqrtf(acc + EPSI);
}

// ---- xs[b][p][ci] = bf16(style[b][ci] * x[b][ci][p])   (transpose to ci-innermost)
__global__ void k_xs(const float* __restrict__ x, const float* __restrict__ style,
                     __hip_bfloat16* __restrict__ xs) {
    __shared__ float tile[32][33];
    int b = blockIdx.z, c0 = blockIdx.y * 32, p0 = blockIdx.x * 32;
    int tx = threadIdx.x & 31, ty = threadIdx.x >> 5;
#pragma unroll
    for (int i = 0; i < 4; ++i) {
        int ci = c0 + ty + i * 8;
        tile[ty + i * 8][tx] = x[(b * CI + ci) * HW + p0 + tx] * style[b * CI + ci];
    }
    __syncthreads();
#pragma unroll
    for (int i = 0; i < 4; ++i) {
        int p = p0 + ty + i * 8;
        xs[(b * HW + p) * CI + c0 + tx] = __float2bfloat16(tile[tx][ty + i * 8]);
    }
}

// ---- conv: 1 block = 128co x 128px x 2 batches; 8 waves (2/SIMD), per-wave 64co x 64px
// T3/T4 schedule: raw s_barrier + counted vmcnt; X double-buffer, W triple-buffer (depth-2)
#define XS_BYTES 52224               // one X buffer: 2 batches x 6 rows x 34 cols x 128 B
#define WBUF_BYTES 16384             // one W buffer: 128co x 64ci bf16
#define SMEM_TOTAL (2 * XS_BYTES + 3 * WBUF_BYTES)   // 153600

extern "C" __global__ __launch_bounds__(512, 2) void k_conv(
        const __hip_bfloat16* __restrict__ wtb,
        const __hip_bfloat16* __restrict__ xs,
        const float* __restrict__ dvec,
        const char* __restrict__ zpage,
        float* __restrict__ out) {
    extern __shared__ char smem[];
    char* Xs  = smem;                    // 2 buffers
    char* Wsb = smem + 2 * XS_BYTES;     // 3 buffers

    const int tid  = threadIdx.x;
    const int lane = tid & 63;
    const int wv   = tid >> 6;           // 0..7
    const int wb   = wv >> 2;            // batch within pair
    const int wr   = (wv >> 1) & 1;      // co half (64)
    const int wn   = wv & 1;             // px half (64)

    // XCD-aware swizzle: co-tile pinned per XCD pair so W tile stays L2-resident
    int bid = blockIdx.x;
    int xcd = bid & 7, idx = bid >> 3;
    int cot = xcd >> 1;
    int px8 = idx & 7;
    int bp  = (idx >> 3) | ((xcd & 1) << 2);
    const int co0 = cot * 128;
    const int p0  = px8 * 128;
    const int y0  = px8 * 4;
    const int b0  = bp * 2;
    const int b   = b0 + wb;

    // zero halo pad columns rx=0 and rx=33 in BOTH X buffers (stay zero for whole kernel)
    if (tid < 192) {
        int g = tid & 7;
        int rx = ((tid >> 3) & 1) ? 33 : 0;
        int row = tid >> 4;                  // bb*6+ry, 0..11
        int off = (row * 34 + rx) * 128 + g * 16;
        *(u32x4*)(Xs + off) = (u32x4){0, 0, 0, 0};
        *(u32x4*)(Xs + XS_BYTES + off) = (u32x4){0, 0, 0, 0};
    }

    const int srcgW = (lane & 7) ^ (lane >> 3);

    // W stage: 16 segments, 2 per wave. tap t -> buffer t%3
    auto issueW = [&](int tap, int cin, int bufi) {
        const __hip_bfloat16* wsrc = wtb + ((size_t)tap * CO + co0) * CI + cin;
        char* wdst = Wsb + bufi * WBUF_BYTES;
#pragma unroll
        for (int k = 0; k < 2; ++k) {
            int seg = k * 8 + wv;
            int co_l = seg * 8 + (lane >> 3);
            GLOAD_LDS16(wsrc + co_l * CI + srcgW * 8, wdst + seg * 1024);
        }
    };
    // X stage: 48 segments, 6 per wave; OOB rows stream zeros from zpage (uniform ledger)
    auto issueX = [&](char* Xdst, int cin) {
#pragma unroll
        for (int k = 0; k < 6; ++k) {
            int sid = k * 8 + wv;
            int bb = (sid >= 24) ? 1 : 0;
            int rem = sid - bb * 24;
            int ry = rem >> 2, seg = rem & 3;
            int rx0 = 1 + seg * 8;
            char* ldst = Xdst + ((bb * 6 + ry) * 34 + rx0) * 128;
            int y = y0 - 1 + ry;
            int rx = rx0 + (lane >> 3);
            int srcg = (lane & 7) ^ (rx & 7);
            if ((unsigned)y < 32u)
                GLOAD_LDS16(xs + ((size_t)(b0 + bb) * HW + (y << 5) + (rx - 1)) * CI + cin + srcg * 8, ldst);
            else
                GLOAD_LDS16(zpage, ldst);   // uniform zero source
        }
    };

    f32x16 acc[2][2];
#pragma unroll
    for (int m = 0; m < 2; ++m)
#pragma unroll
        for (int n = 0; n < 2; ++n)
            acc[m][n] = (f32x16)(0.f);

    // ---- prologue: W(0)->buf0, W(1)->buf1, X(0)->Xbuf0; full drain; barrier
    issueW(0, 0, 0);
    issueW(1, 0, 1);
    issueX(Xs, 0);
    SCHED0();
    asm volatile("s_waitcnt lgkmcnt(0) vmcnt(0)" ::: "memory");
    SCHED0();
    SBAR();
    SCHED0();

    for (int cc = 0; cc < 8; ++cc) {
        const char* Xcur = Xs + (cc & 1) * XS_BYTES;
#pragma unroll
        for (int t = 0; t < 9; ++t) {
            // ---- post-barrier issue region: W(s+2) depth-2, X(cc+1) at tap0
            if (!(cc == 7 && t >= 7)) {
                const int tn  = (t <= 6) ? (t + 2) : (t - 7);
                const int cin = ((t <= 6) ? cc : (cc + 1)) * 64;
                issueW(tn, cin, (t + 2) % 3);
            }
            if (t == 0 && cc < 7)
                issueX(Xs + ((cc + 1) & 1) * XS_BYTES, (cc + 1) * 64);
            SCHED0();

            // ---- compute tap t from W buffer t%3
            const char* Wb = Wsb + (t % 3) * WBUF_BYTES;
            const int ky = t / 3, kx = t - (t / 3) * 3;
            __builtin_amdgcn_s_setprio(1);
#pragma unroll
            for (int q = 0; q < 4; ++q) {
                bf16x8 afr[2], bfr[2];
                int g = (q << 1) + (lane >> 5);
#pragma unroll
                for (int m = 0; m < 2; ++m) {
                    int cr = wr * 64 + m * 32 + (lane & 31);
                    afr[m] = *(const bf16x8*)(Wb + cr * 128 + ((g ^ (cr & 7)) << 4));
                }
#pragma unroll
                for (int n = 0; n < 2; ++n) {
                    int ry = wn * 2 + n + ky;
                    int rx = (lane & 31) + kx;
                    bfr[n] = *(const bf16x8*)(Xcur + ((wb * 6 + ry) * 34 + rx) * 128 +
                                              ((g ^ (rx & 7)) << 4));
                }
#pragma unroll
                for (int m = 0; m < 2; ++m)
#pragma unroll
                    for (int n = 0; n < 2; ++n)
                        acc[m][n] = __builtin_amdgcn_mfma_f32_32x32x16_bf16(afr[m], bfr[n], acc[m][n], 0, 0, 0);
            }
            __builtin_amdgcn_s_setprio(0);

            // ---- pre-barrier counted wait (uniform per-wave ledger, in-order retire):
            // cc<7:  t=0,1 -> after W(t+1): W(t+2)(2) + X'(6) = 8 ; t>=2 -> 2
            // cc==7: t<7 -> 2 ; t==7 -> 0 (last W) ; t==8 -> no barrier
            if (!(cc == 7 && t == 8)) {
                SCHED0();
                if (cc < 7 && t < 2)
                    asm volatile("s_waitcnt lgkmcnt(0) vmcnt(8)" ::: "memory");
                else if (cc == 7 && t == 7)
                    asm volatile("s_waitcnt lgkmcnt(0) vmcnt(0)" ::: "memory");
                else
                    asm volatile("s_waitcnt lgkmcnt(0) vmcnt(2)" ::: "memory");
                SCHED0();
                SBAR();
                SCHED0();
            }
        }
    }

    // epilogue: d-scale + store f32. 32x32 C layout: col=lane&31, row=(r&3)+8*(r>>2)+4*(lane>>5)
#pragma unroll
    for (int m = 0; m < 2; ++m) {
#pragma unroll
        for (int r = 0; r < 16; ++r) {
            int co = co0 + wr * 64 + m * 32 + (r & 3) + ((r >> 2) << 3) + ((lane >> 5) << 2);
            float dvv = dvec[b * CO + co];
            float* orow = out + ((size_t)b * CO + co) * HW + p0 + wn * 64;
            orow[lane & 31]        = acc[m][0][r] * dvv;
            orow[32 + (lane & 31)] = acc[m][1][r] * dvv;
        }
    }
}

extern "C" void kernel_launch(void* const* d_in, const int* in_sizes, int n_in,
                              void* d_out, int out_size, void* d_ws, size_t ws_size,
                              hipStream_t stream) {
    const float* x  = (const float*)d_in[0];
    const float* w  = (const float*)d_in[1];
    const float* sw = (const float*)d_in[2];
    const float* sb = (const float*)d_in[3];
    const float* wt = (const float*)d_in[4];
    float* out = (float*)d_out;

    char* ws = (char*)d_ws;
    float* style = (float*)(ws);                               // 32 KB
    float* dvec  = (float*)(ws + 32768);                       // 32 KB
    float* wsq   = (float*)(ws + 65536);                       // 1 MB
    __hip_bfloat16* wtb = (__hip_bfloat16*)(ws + 1114112);     // 4.72 MB
    __hip_bfloat16* xsb = (__hip_bfloat16*)(ws + 5832704);     // 16.78 MB
    char* zpage = ws + 22609920;                               // 1 KB zero page

    hipFuncSetAttribute((const void*)k_conv,
                        hipFuncAttributeMaxDynamicSharedMemorySize, SMEM_TOTAL);

    k_style2<<<2048, 256, 0, stream>>>(w, sw, sb, style);
    k_wprep<<<1024, 256, 0, stream>>>(wt, wsq, (__hip_bfloat16*)wtb, (u32x4*)zpage);
    k_xs<<<dim3(32, 16, 16), 256, 0, stream>>>(x, style, xsb);
    k_demod2<<<2048, 256, 0, stream>>>(style, wsq, dvec);
    k_conv<<<256, 512, SMEM_TOTAL, stream>>>(wtb, xsb, dvec, zpage, out);
}